// Round 1
// baseline (126.934 us; speedup 1.0000x reference)
//
#include <hip/hip_runtime.h>

// Problem constants (match reference setup_inputs).
#define BB 4
#define CC 128
#define CE 64
#define VV 4096
#define NLEV 14   // MAX_LEVELS

// ---------------------------------------------------------------------------
// Kernel 1 (prep): fused
//   blocks [0, BB):        per-batch counting sort of nodes by level
//   blocks [BB, ...):      edge weights w[b,i] = exp(-||e_s[i]-e_s[par(i)]||^2)
//                          one 64-lane wave per node, lane = embed channel.
// ---------------------------------------------------------------------------
__global__ __launch_bounds__(256) void prep_kernel(
    const float* __restrict__ embed,
    const int*  __restrict__ sorted_index,
    const int*  __restrict__ sorted_parent,
    const int*  __restrict__ node_level,
    float* __restrict__ w_ws,        // [BB*VV]
    int*   __restrict__ levelorder,  // [BB*VV]
    int*   __restrict__ offsets)     // [BB*16], entries 0..NLEV used
{
    int tid = threadIdx.x;
    if (blockIdx.x < BB) {
        int b = blockIdx.x;
        __shared__ int hist[NLEV];
        __shared__ int base[NLEV + 1];
        __shared__ int cursor[NLEV];
        if (tid < NLEV) hist[tid] = 0;
        __syncthreads();
        for (int v = tid; v < VV; v += 256) {
            int d = node_level[b * VV + v];
            if (d >= 0 && d < NLEV) atomicAdd(&hist[d], 1);
        }
        __syncthreads();
        if (tid == 0) {
            int acc = 0;
            for (int d = 0; d < NLEV; ++d) { base[d] = acc; cursor[d] = acc; acc += hist[d]; }
            base[NLEV] = acc;
        }
        __syncthreads();
        for (int v = tid; v < VV; v += 256) {
            int d = node_level[b * VV + v];
            if (d >= 0 && d < NLEV) {
                int pos = atomicAdd(&cursor[d], 1);
                levelorder[b * VV + pos] = v;
            }
        }
        if (tid <= NLEV) offsets[b * 16 + tid] = base[tid];
    } else {
        // one wave per node; lane = embed channel (CE == 64 == wave size)
        int lane = tid & 63;
        int wv   = tid >> 6;
        long g = (long)(blockIdx.x - BB) * 4 + wv;   // node index in [0, BB*VV)
        if (g >= (long)BB * VV) return;
        int b = (int)(g >> 12);          // VV = 4096 = 2^12
        int i = (int)(g & (VV - 1));
        int vi = sorted_index[b * VV + i];
        int p  = sorted_parent[b * VV + i];
        int vp = sorted_index[b * VV + p];
        const float* eb = embed + (size_t)b * CE * VV;
        float diff = eb[(size_t)lane * VV + vi] - eb[(size_t)lane * VV + vp];
        float d2 = diff * diff;
        #pragma unroll
        for (int o = 32; o > 0; o >>= 1) d2 += __shfl_xor(d2, o, 64);
        if (lane == 0) w_ws[b * VV + i] = __expf(-d2);
    }
}

// ---------------------------------------------------------------------------
// Kernel 2 (tree): one block per (b, c). Whole per-channel chain in LDS.
//   val[V]: feature aggregate; vn[V]: normalizer chain (redundant per block).
//   Up-pass:   levels 13..1, LDS atomicAdd into parent slots (level d-1).
//   Down-pass: levels 1..13, in-place (level-d writes never alias level-(d-1)
//              parent reads; own slot read-then-write is same-thread).
// ---------------------------------------------------------------------------
__global__ __launch_bounds__(256) void tree_kernel(
    const float* __restrict__ feat,
    const int*  __restrict__ sorted_index,
    const int*  __restrict__ sorted_parent,
    const float* __restrict__ w_ws,
    const int*  __restrict__ levelorder,
    const int*  __restrict__ offsets,
    float* __restrict__ out)
{
    __shared__ float val[VV];
    __shared__ float vn[VV];
    int blk = blockIdx.x;
    int b = blk / CC;
    int c = blk % CC;
    int tid = threadIdx.x;

    const int*   si  = sorted_index  + b * VV;
    const int*   par = sorted_parent + b * VV;
    const float* wb  = w_ws          + b * VV;
    const int*   lo  = levelorder    + b * VV;
    const int*   off = offsets       + b * 16;
    const float* f   = feat + ((size_t)b * CC + c) * VV;

    // init: val = f gathered by sorted_index, vn = 1
    for (int v = tid; v < VV; v += 256) {
        val[v] = f[si[v]];
        vn[v]  = 1.0f;
    }
    __syncthreads();

    // upward: deepest level first; children finished before parent is pushed
    for (int d = NLEV - 1; d >= 1; --d) {
        int s = off[d], e = off[d + 1];
        for (int k = s + tid; k < e; k += 256) {
            int i = lo[k];
            int p = par[i];
            float wi = wb[i];
            atomicAdd(&val[p], wi * val[i]);
            atomicAdd(&vn[p],  wi * vn[i]);
        }
        __syncthreads();
    }

    // downward: level 1..13, in place. val[p] already final (level d-1).
    for (int d = 1; d <= NLEV - 1; ++d) {
        int s = off[d], e = off[d + 1];
        for (int k = s + tid; k < e; k += 256) {
            int i = lo[k];
            int p = par[i];
            float wi = wb[i];
            float u  = val[i];
            float un = vn[i];
            val[i] = fmaf(wi, val[p] - wi * u,  u);
            vn[i]  = fmaf(wi, vn[p]  - wi * un, un);
        }
        __syncthreads();
    }

    // normalize + unsort scatter
    float* ob = out + ((size_t)b * CC + c) * VV;
    for (int v = tid; v < VV; v += 256) {
        ob[si[v]] = val[v] / vn[v];
    }
}

extern "C" void kernel_launch(void* const* d_in, const int* in_sizes, int n_in,
                              void* d_out, int out_size, void* d_ws, size_t ws_size,
                              hipStream_t stream) {
    const float* feat          = (const float*)d_in[0];
    const float* embed         = (const float*)d_in[1];
    const int*   sorted_index  = (const int*)d_in[2];
    const int*   sorted_parent = (const int*)d_in[3];
    const int*   node_level    = (const int*)d_in[4];
    float* out = (float*)d_out;

    char* ws = (char*)d_ws;
    float* w_ws       = (float*)ws;                         // BB*VV floats (64 KB)
    int*   levelorder = (int*)(ws + (size_t)BB * VV * 4);   // BB*VV ints   (64 KB)
    int*   offsets    = (int*)(ws + (size_t)2 * BB * VV * 4); // BB*16 ints (256 B)

    int wblocks = (BB * VV + 3) / 4;   // 4 waves (nodes) per 256-thread block
    prep_kernel<<<BB + wblocks, 256, 0, stream>>>(
        embed, sorted_index, sorted_parent, node_level, w_ws, levelorder, offsets);

    tree_kernel<<<BB * CC, 256, 0, stream>>>(
        feat, sorted_index, sorted_parent, w_ws, levelorder, offsets, out);
}